// Round 15
// baseline (79.327 us; speedup 1.0000x reference)
//
#include <hip/hip_runtime.h>
#include <hip/hip_bf16.h>

typedef __bf16 bf16_t;
typedef bf16_t bf16x8 __attribute__((ext_vector_type(8)));
typedef bf16_t bf16x4 __attribute__((ext_vector_type(4)));
typedef float f32x4 __attribute__((ext_vector_type(4)));

#define MFMA16(a, b, c) __builtin_amdgcn_mfma_f32_16x16x32_bf16((a), (b), (c), 0, 0, 0)

// B=8, T=2048, E=1024, H=128
#define TT 2048
#define EE 1024
#define HH 128
#define UPB 288   // partial slots per batch: sum over 64 qtiles of (qt>>3)+1

// Fragment-major layouts (every consumer load = one coalesced 64x16B instr):
//  Wf: chunk(ct,kt): lane(g,c) elem e = W_{ct>>3}[k=kt*32+g*8+e][n=(ct&7)*16+c]
//  Qf/Kf: chunk(grt,kk): lane(g,c) elem e = M[grt*16+c][kk*32+g*8+e]
//  Vf: chunk(b,vc,hb): lane(g,c) elem j = V[b][vc*32+g*8+j][hb*16+c]

// ---------------- prep: Wf fragment-major, f32 -> bf16 ----------------
__global__ __launch_bounds__(256) void prep_w_kernel(
    const float* __restrict__ Wq, const float* __restrict__ Wk,
    const float* __restrict__ Wv, bf16_t* __restrict__ Wf)
{
    int idx = blockIdx.x * 256 + threadIdx.x;   // 0 .. 393215
    int e  = idx & 7;
    int c  = (idx >> 3) & 15;
    int g  = (idx >> 7) & 3;
    int kt = (idx >> 9) & 31;
    int ct = idx >> 14;                          // 0..23
    int w  = ct >> 3;
    const float* W = (w == 0) ? Wq : (w == 1) ? Wk : Wv;
    int k = kt * 32 + g * 8 + e;
    int n = (ct & 7) * 16 + c;
    Wf[idx] = (bf16_t)W[k * HH + n];
}

// ---------------- fused QKV GEMM: [16384 x 1024] x [1024 x 384] ----------------
// BARRIER-FREE: 2048 fully independent waves (512 blocks x 4 waves); each wave
// owns a 16-row x 192-col output strip. Per K-step: 2 coalesced f32 loads ->
// wave-PRIVATE LDS slab ([16][36] f32, transpose bounce, intra-wave lgkmcnt
// ordering only) -> 1 bf16x8 A-frag -> 12 MFMA vs double-reg-buffered
// fragment-major W. nhalf pair shares a block => x rows L1-local, read once.
__global__ __launch_bounds__(256) void qkv_kernel(
    const float* __restrict__ x, const bf16_t* __restrict__ Wf,
    bf16_t* __restrict__ Qf, bf16_t* __restrict__ Kf, bf16_t* __restrict__ Vf)
{
    __shared__ __attribute__((aligned(16))) float As[4][2][16][36];
    const int tid = threadIdx.x, lane = tid & 63, wid = tid >> 6;
    const int g = lane >> 4, c = lane & 15;

    const int gw    = blockIdx.x * 4 + wid;      // global wave id 0..2047
    const int grt   = gw >> 1;                   // 16-row strip 0..1023
    const int nhalf = gw & 1;                    // 192-col half
    const int row0  = grt * 16;

    // x load: lane l -> row l>>2, 32B slot l&3 (16 x 128B segments, coalesced)
    const int xr = lane >> 2, xs = lane & 3;
    const float* xp = x + (size_t)(row0 + xr) * EE + xs * 8;

    float (*L)[16][36] = As[wid];                // wave-private double buffer

    // W frags: ct = nhalf*12 + nt; chunk (ct,kt) at (ct*32+kt)*512
    const bf16_t* wfb = Wf + ((size_t)(nhalf * 12) * 32) * 512 + lane * 8;

    f32x4 acc[12];
    for (int j = 0; j < 12; ++j) acc[j] = (f32x4)0.0f;

    f32x4 xa[2][2];                              // [pipeline set][16B half]
    bf16x8 w[2][12];

#define XLOAD(S, T) do {                                                      \
    xa[S][0] = *(const f32x4*)(xp + (size_t)(T) * 32);                        \
    xa[S][1] = *(const f32x4*)(xp + (size_t)(T) * 32 + 4);                    \
} while (0)
#define WLOAD(S, T)                                                           \
    for (int nt = 0; nt < 12; ++nt)                                           \
        w[S][nt] = *(const bf16x8*)(wfb + ((size_t)nt * 32 + (T)) * 512);
#define XWRITE(S, BUF) do {                                                   \
    *(f32x4*)&L[BUF][xr][xs * 8]     = xa[S][0];                              \
    *(f32x4*)&L[BUF][xr][xs * 8 + 4] = xa[S][1];                              \
} while (0)
#define COMPUTE(BUF, S) do {                                                  \
    f32x4 r0 = *(const f32x4*)&L[BUF][c][g * 8];                              \
    f32x4 r1 = *(const f32x4*)&L[BUF][c][g * 8 + 4];                          \
    union { bf16_t h[8]; bf16x8 v; } u_;                                      \
    for (int j = 0; j < 4; ++j) {                                             \
        u_.h[j]     = (bf16_t)r0[j];                                          \
        u_.h[4 + j] = (bf16_t)r1[j];                                          \
    }                                                                         \
    for (int nt = 0; nt < 12; ++nt)                                           \
        acc[nt] = MFMA16(u_.v, w[S][nt], acc[nt]);                            \
} while (0)

    // prologue: tiles 0,1 in regs; W frags 0,1; tile0 -> buf0
    XLOAD(0, 0);
    XLOAD(1, 1);
    WLOAD(0, 0);
    WLOAD(1, 1);
    XWRITE(0, 0);

    for (int t = 0; t < 32; t += 2) {
        if (t + 2 < 32) XLOAD(0, t + 2);         // issue x tile t+2
        XWRITE(1, 1);                            // tile t+1 -> buf1 (DS in-order)
        COMPUTE(0, 0);                           // tile t from buf0
        if (t + 2 < 32) WLOAD(0, t + 2);
        if (t + 3 < 32) XLOAD(1, t + 3);
        if (t + 2 < 32) XWRITE(0, 0);            // tile t+2 -> buf0 (after reads)
        COMPUTE(1, 1);                           // tile t+1 from buf1
        if (t + 3 < 32) WLOAD(1, t + 3);
    }
#undef XLOAD
#undef WLOAD
#undef XWRITE
#undef COMPUTE

    const float sc = 0.08838834764831845f * 1.4426950408889634f; // 1/sqrt(128)*log2e
    for (int nt = 0; nt < 12; ++nt) {
        int cb = nhalf * 192 + nt * 16;
        int w_ = cb >> 7;
        int hl = (cb & 127) + c;                 // col within Q/K/V
        int t0 = row0 + g * 4;                   // global row
        if (w_ == 2) {
            int b  = t0 >> 11;
            int ttr = t0 & (TT - 1);
            int vc = ttr >> 5, gg = (ttr & 31) >> 3, j0 = ttr & 7;
            int hb = hl >> 4, cc = hl & 15;
            union { bf16_t h4[4]; unsigned long long u; } pk;
            for (int i = 0; i < 4; ++i) pk.h4[i] = (bf16_t)acc[nt][i];
            *reinterpret_cast<unsigned long long*>(
                Vf + ((size_t)((b * 64 + vc) * 8 + hb)) * 512 +
                (gg * 16 + cc) * 8 + j0) = pk.u;
        } else {
            bf16_t* dst = (w_ == 0) ? Qf : Kf;
            float s = (w_ == 0) ? sc : 1.0f;
            int kk = hl >> 5, gg = (hl & 31) >> 3, e = hl & 7;
            for (int i = 0; i < 4; ++i) {
                int cr = (t0 + i) & 15;
                dst[((size_t)(grt * 4 + kk)) * 512 + (gg * 16 + cr) * 8 + e] =
                    (bf16_t)(acc[nt][i] * s);
            }
        }
    }
}

// ---------------- flash attention, split-KV partials, fragment-major I/O ----------------
// unit = (b, 32-row qtile, kvchunk256); one wave per unit, 4 units/block.
// blockIdx&7 = b -> XCD-pinned batch. Every Q/K/V load = 1 coalesced 1KB instr.
__global__ __launch_bounds__(256) void attn_kernel(
    const bf16_t* __restrict__ Qf, const bf16_t* __restrict__ Kf,
    const bf16_t* __restrict__ Vf, bf16_t* __restrict__ Pacc,
    float* __restrict__ Pml)
{
    __shared__ __attribute__((aligned(16))) bf16_t Pl[4][32][40];
    const int tid = threadIdx.x, lane = tid & 63, wid = tid >> 6;
    const int g = lane >> 4, c = lane & 15;
    bf16_t (*P)[40] = Pl[wid];

    const int bx = blockIdx.x;
    const int b  = bx & 7;                       // XCD-pinned batch
    const int u  = 287 - ((bx >> 3) * 4 + wid);  // long-units-first
    int k = 0;
    while (4 * (k + 1) * (k + 2) <= u) ++k;      // tier k = qt>>3, 0..7
    const int r  = u - 4 * k * (k + 1);
    const int qt = 8 * k + r / (k + 1);
    const int ch = r - (r / (k + 1)) * (k + 1);
    const int q0 = qt * 32;
    const int kv_lo = ch * 256;
    int kv_hi = kv_lo + 256; if (kv_hi > q0 + 32) kv_hi = q0 + 32;
    const int sid = b * UPB + 4 * k * (k + 1) + (qt & 7) * (k + 1) + ch;

    bf16x8 qA[4], qB[4];
    for (int kk = 0; kk < 4; ++kk) {
        qA[kk] = *(const bf16x8*)(Qf +
            ((size_t)((b * 128 + (q0 >> 4)) * 4 + kk)) * 512 + lane * 8);
        qB[kk] = *(const bf16x8*)(Qf +
            ((size_t)((b * 128 + (q0 >> 4) + 1) * 4 + kk)) * 512 + lane * 8);
    }

    f32x4 accA[8], accB[8];
    for (int hb = 0; hb < 8; ++hb) { accA[hb] = (f32x4)0.0f; accB[hb] = (f32x4)0.0f; }
    float lsA[4] = {0, 0, 0, 0}, lsB[4] = {0, 0, 0, 0};

    for (int kv0 = kv_lo; kv0 < kv_hi; kv0 += 32) {
        const int kt = b * 128 + (kv0 >> 4);
        bf16x8 k0f[4], k1f[4], vf[8];
        for (int kk = 0; kk < 4; ++kk) {
            k0f[kk] = *(const bf16x8*)(Kf + ((size_t)(kt * 4 + kk)) * 512 + lane * 8);
            k1f[kk] = *(const bf16x8*)(Kf + ((size_t)((kt + 1) * 4 + kk)) * 512 + lane * 8);
        }
        const int vcb = (b * 64 + (kv0 >> 5)) * 8;
        for (int hb = 0; hb < 8; ++hb)
            vf[hb] = *(const bf16x8*)(Vf + ((size_t)(vcb + hb)) * 512 + lane * 8);

        f32x4 sA0 = (f32x4)0.0f, sA1 = (f32x4)0.0f;
        f32x4 sB0 = (f32x4)0.0f, sB1 = (f32x4)0.0f;
        for (int kk = 0; kk < 4; ++kk) {
            sA0 = MFMA16(qA[kk], k0f[kk], sA0);
            sA1 = MFMA16(qA[kk], k1f[kk], sA1);
            sB0 = MFMA16(qB[kk], k0f[kk], sB0);
            sB1 = MFMA16(qB[kk], k1f[kk], sB1);
        }
        if (kv0 + 32 > q0) {                     // causal mask, subtile A
            for (int i = 0; i < 4; ++i) {
                int row = q0 + g * 4 + i;
                if (kv0 + c > row)      sA0[i] = -1e30f;
                if (kv0 + 16 + c > row) sA1[i] = -1e30f;
            }
        }
        if (kv0 + 32 > q0 + 16) {                // causal mask, subtile B
            for (int i = 0; i < 4; ++i) {
                int row = q0 + 16 + g * 4 + i;
                if (kv0 + c > row)      sB0[i] = -1e30f;
                if (kv0 + 16 + c > row) sB1[i] = -1e30f;
            }
        }
        float pA0[4], pA1[4], pB0[4], pB1[4];
        for (int i = 0; i < 4; ++i) {            // p = 2^s (log2e folded into Q)
            pA0[i] = exp2f(sA0[i]); pA1[i] = exp2f(sA1[i]);
            pB0[i] = exp2f(sB0[i]); pB1[i] = exp2f(sB1[i]);
            lsA[i] += pA0[i] + pA1[i];
            lsB[i] += pB0[i] + pB1[i];
        }
        for (int i = 0; i < 4; ++i) {
            P[g * 4 + i][c]           = (bf16_t)pA0[i];
            P[g * 4 + i][c + 16]      = (bf16_t)pA1[i];
            P[16 + g * 4 + i][c]      = (bf16_t)pB0[i];
            P[16 + g * 4 + i][c + 16] = (bf16_t)pB1[i];
        }
        __builtin_amdgcn_wave_barrier();
        asm volatile("s_waitcnt lgkmcnt(0)" ::: "memory");
        __builtin_amdgcn_sched_barrier(0);
        bf16x8 paA = *(const bf16x8*)&P[c][g * 8];
        bf16x8 paB = *(const bf16x8*)&P[16 + c][g * 8];
        __builtin_amdgcn_s_setprio(1);
        for (int hb = 0; hb < 8; ++hb) {
            accA[hb] = MFMA16(paA, vf[hb], accA[hb]);
            accB[hb] = MFMA16(paB, vf[hb], accB[hb]);
        }
        __builtin_amdgcn_s_setprio(0);
        __builtin_amdgcn_wave_barrier();
    }

    for (int off = 1; off < 16; off <<= 1)
        for (int i = 0; i < 4; ++i) {
            lsA[i] += __shfl_xor(lsA[i], off, 64);
            lsB[i] += __shfl_xor(lsB[i], off, 64);
        }
    if (c == 0)
        for (int i = 0; i < 4; ++i) {
            Pml[(size_t)sid * 32 + g * 4 + i]      = lsA[i];
            Pml[(size_t)sid * 32 + 16 + g * 4 + i] = lsB[i];
        }

    // Pacc transposed: po[col=128][row=32]; packed 8B stores
    bf16_t* po = Pacc + (size_t)sid * (32 * 128);
    for (int hb = 0; hb < 8; ++hb) {
        union { bf16_t h4[4]; unsigned long long u; } pa, pb;
        for (int i = 0; i < 4; ++i) {
            pa.h4[i] = (bf16_t)accA[hb][i];
            pb.h4[i] = (bf16_t)accB[hb][i];
        }
        bf16_t* cp = po + (hb * 16 + c) * 32;
        *reinterpret_cast<unsigned long long*>(cp + g * 4)      = pa.u;
        *reinterpret_cast<unsigned long long*>(cp + 16 + g * 4) = pb.u;
    }
}

// ---------------- combine partials (plain sums; Pacc is [col][row]) ----------------
__global__ __launch_bounds__(128) void combine_kernel(
    const bf16_t* __restrict__ Pacc, const float* __restrict__ Pml,
    float* __restrict__ out)
{
    __shared__ float invL[32];
    const int qt = blockIdx.x;                   // 0..63
    const int b  = blockIdx.y;
    const int k  = qt >> 3;
    const int base  = b * UPB + 4 * k * (k + 1) + (qt & 7) * (k + 1);
    const int count = k + 1;
    const int tid = threadIdx.x;                 // = col 0..127

    if (tid < 32) {
        float L = 0.0f;
        for (int cu = 0; cu < count; ++cu)
            L += Pml[(size_t)(base + cu) * 32 + tid];
        invL[tid] = 1.0f / L;
    }
    __syncthreads();

    float s[32];
    for (int r = 0; r < 32; ++r) s[r] = 0.0f;
    for (int cu = 0; cu < count; ++cu) {
        const bf16_t* cp = Pacc + (size_t)(base + cu) * 4096 + tid * 32;
        for (int r8 = 0; r8 < 4; ++r8) {
            bf16x8 v = *(const bf16x8*)(cp + r8 * 8);
            for (int j = 0; j < 8; ++j) s[r8 * 8 + j] += (float)v[j];
        }
    }
    const int q0 = qt * 32;
    for (int r = 0; r < 32; ++r)
        out[((size_t)b * TT + q0 + r) * HH + tid] = s[r] * invL[r];
}

extern "C" void kernel_launch(void* const* d_in, const int* in_sizes, int n_in,
                              void* d_out, int out_size, void* d_ws, size_t ws_size,
                              hipStream_t stream)
{
    const float* x  = (const float*)d_in[0];
    const float* Wq = (const float*)d_in[1];
    const float* Wk = (const float*)d_in[2];
    const float* Wv = (const float*)d_in[3];

    char* ws = (char*)d_ws;
    bf16_t* Wf   = (bf16_t*)ws;                       // 768 KB fragment-major
    bf16_t* Qf   = (bf16_t*)(ws + (1u  << 20));       // 4 MB fragment-major
    bf16_t* Kf   = (bf16_t*)(ws + (5u  << 20));       // 4 MB fragment-major
    bf16_t* Vf   = (bf16_t*)(ws + (9u  << 20));       // 4 MB fragment-major
    bf16_t* Pacc = (bf16_t*)(ws + (13u << 20));       // 2304*8192 B = 18.9 MB
    float*  Pml  = (float*) (ws + (32u << 20));       // 2304*128 B

    prep_w_kernel<<<1536, 256, 0, stream>>>(Wq, Wk, Wv, Wf);
    qkv_kernel<<<512, 256, 0, stream>>>(x, Wf, Qf, Kf, Vf);
    attn_kernel<<<576, 256, 0, stream>>>(Qf, Kf, Vf, Pacc, Pml);
    combine_kernel<<<dim3(64, 8), 128, 0, stream>>>(Pacc, Pml, (float*)d_out);
}

// Round 16
// 66.625 us; speedup vs baseline: 1.1906x; 1.1906x over previous
//
#include <hip/hip_runtime.h>
#include <hip/hip_bf16.h>

typedef __bf16 bf16_t;
typedef bf16_t bf16x8 __attribute__((ext_vector_type(8)));
typedef bf16_t bf16x4 __attribute__((ext_vector_type(4)));
typedef float f32x4 __attribute__((ext_vector_type(4)));

#define MFMA16(a, b, c) __builtin_amdgcn_mfma_f32_16x16x32_bf16((a), (b), (c), 0, 0, 0)

// B=8, T=2048, E=1024, H=128
#define TT 2048
#define EE 1024
#define HH 128
#define UPB 288   // partial slots per batch: sum over 64 qtiles of (qt>>3)+1

// Fragment-major layouts (every consumer load = one coalesced 64x16B instr):
//  Wf: chunk(ct,kt): lane(g,c) elem e = W_{ct>>3}[k=kt*32+g*8+e][n=(ct&7)*16+c]
//  Qf/Kf: chunk(grt,kk): lane(g,c) elem e = M[grt*16+c][kk*32+g*8+e]
//  Vf: chunk(b,vc,hb): lane(g,c) elem j = V[b][vc*32+g*8+j][hb*16+c]

// ---------------- prep: Wf fragment-major, f32 -> bf16 ----------------
__global__ __launch_bounds__(256) void prep_w_kernel(
    const float* __restrict__ Wq, const float* __restrict__ Wk,
    const float* __restrict__ Wv, bf16_t* __restrict__ Wf)
{
    int idx = blockIdx.x * 256 + threadIdx.x;   // 0 .. 393215
    int e  = idx & 7;
    int c  = (idx >> 3) & 15;
    int g  = (idx >> 7) & 3;
    int kt = (idx >> 9) & 31;
    int ct = idx >> 14;                          // 0..23
    int w  = ct >> 3;
    const float* W = (w == 0) ? Wq : (w == 1) ? Wk : Wv;
    int k = kt * 32 + g * 8 + e;
    int n = (ct & 7) * 16 + c;
    Wf[idx] = (bf16_t)W[k * HH + n];
}

// ---------------- fused QKV GEMM: [16384 x 1024] x [1024 x 384] ----------------
// 512 blocks (2/CU) x 256 thr (4 waves); BM=64, BN=192 (wave 64x48), BK=64.
// Depth-3 x register pipeline (x loads ~2 full phases in flight before the
// dependent ds_write), W frags fragment-major double-reg-buffered, raw
// s_barrier + lgkmcnt-only (loads cross barriers), setprio(1) on MFMA cluster.
__global__ __launch_bounds__(256) void qkv_kernel(
    const float* __restrict__ x, const bf16_t* __restrict__ Wf,
    bf16_t* __restrict__ Qf, bf16_t* __restrict__ Kf, bf16_t* __restrict__ Vf)
{
    __shared__ __attribute__((aligned(16))) bf16_t As[2][64][72];  // 144B rows
    const int bx = blockIdx.x;
    const int row0  = (bx & 255) * 64;
    const int nhalf = bx >> 8;
    const int tid  = threadIdx.x;
    const int lane = tid & 63;
    const int wn   = tid >> 6;                    // 4 waves: 48-col slices
    const int g = lane >> 4, c = lane & 15;

    // staging: thread t -> row t>>2 (0..63), 16-f32 colgroup t&3; 4 f32x4 loads
    const int srow = tid >> 2;
    const int scg  = tid & 3;
    const float* xp = x + (size_t)(row0 + srow) * EE + scg * 16;

    // W fragment base: wave wn covers ct = nhalf*12 + wn*3 .. +2
    const bf16_t* wfb = Wf + ((size_t)(nhalf * 12 + wn * 3) * 32) * 512 + lane * 8;

    f32x4 acc[4][3];
    for (int i = 0; i < 4; ++i)
        for (int j = 0; j < 3; ++j) acc[i][j] = (f32x4)0.0f;

    f32x4 xa[3][4];                               // depth-3 x pipeline
    bf16x8 w[2][6];                               // [set][kk*3+j]

#define BAR() do {                                                            \
    asm volatile("s_waitcnt lgkmcnt(0)" ::: "memory");                        \
    __builtin_amdgcn_s_barrier();                                             \
    __builtin_amdgcn_sched_barrier(0);                                        \
} while (0)
#define XLOAD(S, T)                                                           \
    for (int q = 0; q < 4; ++q)                                               \
        xa[S][q] = *(const f32x4*)(xp + (size_t)(T) * 64 + q * 4);
#define WLOAD(S, T)                                                           \
    for (int kk = 0; kk < 2; ++kk)                                            \
        for (int j = 0; j < 3; ++j)                                           \
            w[S][kk * 3 + j] = *(const bf16x8*)(wfb +                         \
                ((size_t)j * 32 + (T) * 2 + kk) * 512);
#define XWRITE(S, BUF) do {                                                   \
    union { bf16_t h[8]; unsigned long long u[2]; } pA_, pB_;                 \
    for (int q = 0; q < 4; ++q) {                                             \
        pA_.h[q]     = (bf16_t)xa[S][0][q];                                   \
        pA_.h[4 + q] = (bf16_t)xa[S][1][q];                                   \
        pB_.h[q]     = (bf16_t)xa[S][2][q];                                   \
        pB_.h[4 + q] = (bf16_t)xa[S][3][q];                                   \
    }                                                                         \
    *reinterpret_cast<unsigned long long*>(&As[BUF][srow][scg * 16])     = pA_.u[0]; \
    *reinterpret_cast<unsigned long long*>(&As[BUF][srow][scg * 16 + 4]) = pA_.u[1]; \
    *reinterpret_cast<unsigned long long*>(&As[BUF][srow][scg * 16 + 8]) = pB_.u[0]; \
    *reinterpret_cast<unsigned long long*>(&As[BUF][srow][scg * 16 +12]) = pB_.u[1]; \
} while (0)

    // prologue: x tiles 0,1,2 in flight; W frags 0,1; tile0 -> buf0
    XLOAD(0, 0);
    XLOAD(1, 1);
    XLOAD(2, 2);
    WLOAD(0, 0);
    WLOAD(1, 1);
    XWRITE(0, 0);
    BAR();

#pragma unroll
    for (int t = 0; t < 16; ++t) {
        const int buf = t & 1;
        if (t + 3 < 16) XLOAD((t + 3) % 3, t + 3);
        __builtin_amdgcn_s_setprio(1);
        for (int kk = 0; kk < 2; ++kk)
            for (int mt = 0; mt < 4; ++mt) {
                bf16x8 af = *(const bf16x8*)&As[buf][mt * 16 + c][kk * 32 + g * 8];
                for (int j = 0; j < 3; ++j)
                    acc[mt][j] = MFMA16(af, w[t & 1][kk * 3 + j], acc[mt][j]);
            }
        __builtin_amdgcn_s_setprio(0);
        if (t + 2 < 16) WLOAD(t & 1, t + 2);     // refill just-freed W set
        if (t + 1 < 16) XWRITE((t + 1) % 3, buf ^ 1);
        BAR();
    }
#undef XLOAD
#undef WLOAD
#undef XWRITE
#undef BAR

    const float sc = 0.08838834764831845f * 1.4426950408889634f; // 1/sqrt(128)*log2e
    for (int mt = 0; mt < 4; ++mt)
        for (int j = 0; j < 3; ++j) {
            int cb = nhalf * 192 + wn * 48 + j * 16;
            int w_ = cb >> 7;
            int hl = (cb & 127) + c;             // col within Q/K/V
            int t0 = row0 + mt * 16 + g * 4;     // global row
            if (w_ == 2) {
                int b  = t0 >> 11;
                int ttr = t0 & (TT - 1);
                int vc = ttr >> 5, gg = (ttr & 31) >> 3, j0 = ttr & 7;
                int hb = hl >> 4, cc = hl & 15;
                union { bf16_t h4[4]; unsigned long long u; } pk;
                for (int i = 0; i < 4; ++i) pk.h4[i] = (bf16_t)acc[mt][j][i];
                *reinterpret_cast<unsigned long long*>(
                    Vf + ((size_t)((b * 64 + vc) * 8 + hb)) * 512 +
                    (gg * 16 + cc) * 8 + j0) = pk.u;
            } else {
                bf16_t* dst = (w_ == 0) ? Qf : Kf;
                float s = (w_ == 0) ? sc : 1.0f;
                int kk = hl >> 5, gg = (hl & 31) >> 3, e = hl & 7;
                int grt = t0 >> 4;
                for (int i = 0; i < 4; ++i) {
                    int cr = (t0 + i) & 15;
                    dst[((size_t)(grt * 4 + kk)) * 512 + (gg * 16 + cr) * 8 + e] =
                        (bf16_t)(acc[mt][j][i] * s);
                }
            }
        }
}

// ---------------- flash attention, split-KV partials, fragment-major I/O ----------------
// unit = (b, 32-row qtile, kvchunk256); one wave per unit, 4 units/block.
// blockIdx&7 = b -> XCD-pinned batch. Every Q/K/V load = 1 coalesced 1KB instr.
__global__ __launch_bounds__(256) void attn_kernel(
    const bf16_t* __restrict__ Qf, const bf16_t* __restrict__ Kf,
    const bf16_t* __restrict__ Vf, bf16_t* __restrict__ Pacc,
    float* __restrict__ Pml)
{
    __shared__ __attribute__((aligned(16))) bf16_t Pl[4][32][40];
    const int tid = threadIdx.x, lane = tid & 63, wid = tid >> 6;
    const int g = lane >> 4, c = lane & 15;
    bf16_t (*P)[40] = Pl[wid];

    const int bx = blockIdx.x;
    const int b  = bx & 7;                       // XCD-pinned batch
    const int u  = 287 - ((bx >> 3) * 4 + wid);  // long-units-first
    int k = 0;
    while (4 * (k + 1) * (k + 2) <= u) ++k;      // tier k = qt>>3, 0..7
    const int r  = u - 4 * k * (k + 1);
    const int qt = 8 * k + r / (k + 1);
    const int ch = r - (r / (k + 1)) * (k + 1);
    const int q0 = qt * 32;
    const int kv_lo = ch * 256;
    int kv_hi = kv_lo + 256; if (kv_hi > q0 + 32) kv_hi = q0 + 32;
    const int sid = b * UPB + 4 * k * (k + 1) + (qt & 7) * (k + 1) + ch;

    bf16x8 qA[4], qB[4];
    for (int kk = 0; kk < 4; ++kk) {
        qA[kk] = *(const bf16x8*)(Qf +
            ((size_t)((b * 128 + (q0 >> 4)) * 4 + kk)) * 512 + lane * 8);
        qB[kk] = *(const bf16x8*)(Qf +
            ((size_t)((b * 128 + (q0 >> 4) + 1) * 4 + kk)) * 512 + lane * 8);
    }

    f32x4 accA[8], accB[8];
    for (int hb = 0; hb < 8; ++hb) { accA[hb] = (f32x4)0.0f; accB[hb] = (f32x4)0.0f; }
    float lsA[4] = {0, 0, 0, 0}, lsB[4] = {0, 0, 0, 0};

    for (int kv0 = kv_lo; kv0 < kv_hi; kv0 += 32) {
        const int kt = b * 128 + (kv0 >> 4);
        bf16x8 k0f[4], k1f[4], vf[8];
        for (int kk = 0; kk < 4; ++kk) {
            k0f[kk] = *(const bf16x8*)(Kf + ((size_t)(kt * 4 + kk)) * 512 + lane * 8);
            k1f[kk] = *(const bf16x8*)(Kf + ((size_t)((kt + 1) * 4 + kk)) * 512 + lane * 8);
        }
        const int vcb = (b * 64 + (kv0 >> 5)) * 8;
        for (int hb = 0; hb < 8; ++hb)
            vf[hb] = *(const bf16x8*)(Vf + ((size_t)(vcb + hb)) * 512 + lane * 8);

        f32x4 sA0 = (f32x4)0.0f, sA1 = (f32x4)0.0f;
        f32x4 sB0 = (f32x4)0.0f, sB1 = (f32x4)0.0f;
        for (int kk = 0; kk < 4; ++kk) {
            sA0 = MFMA16(qA[kk], k0f[kk], sA0);
            sA1 = MFMA16(qA[kk], k1f[kk], sA1);
            sB0 = MFMA16(qB[kk], k0f[kk], sB0);
            sB1 = MFMA16(qB[kk], k1f[kk], sB1);
        }
        if (kv0 + 32 > q0) {                     // causal mask, subtile A
            for (int i = 0; i < 4; ++i) {
                int row = q0 + g * 4 + i;
                if (kv0 + c > row)      sA0[i] = -1e30f;
                if (kv0 + 16 + c > row) sA1[i] = -1e30f;
            }
        }
        if (kv0 + 32 > q0 + 16) {                // causal mask, subtile B
            for (int i = 0; i < 4; ++i) {
                int row = q0 + 16 + g * 4 + i;
                if (kv0 + c > row)      sB0[i] = -1e30f;
                if (kv0 + 16 + c > row) sB1[i] = -1e30f;
            }
        }
        float pA0[4], pA1[4], pB0[4], pB1[4];
        for (int i = 0; i < 4; ++i) {            // p = 2^s (log2e folded into Q)
            pA0[i] = exp2f(sA0[i]); pA1[i] = exp2f(sA1[i]);
            pB0[i] = exp2f(sB0[i]); pB1[i] = exp2f(sB1[i]);
            lsA[i] += pA0[i] + pA1[i];
            lsB[i] += pB0[i] + pB1[i];
        }
        for (int i = 0; i < 4; ++i) {
            P[g * 4 + i][c]           = (bf16_t)pA0[i];
            P[g * 4 + i][c + 16]      = (bf16_t)pA1[i];
            P[16 + g * 4 + i][c]      = (bf16_t)pB0[i];
            P[16 + g * 4 + i][c + 16] = (bf16_t)pB1[i];
        }
        __builtin_amdgcn_wave_barrier();
        asm volatile("s_waitcnt lgkmcnt(0)" ::: "memory");
        __builtin_amdgcn_sched_barrier(0);
        bf16x8 paA = *(const bf16x8*)&P[c][g * 8];
        bf16x8 paB = *(const bf16x8*)&P[16 + c][g * 8];
        __builtin_amdgcn_s_setprio(1);
        for (int hb = 0; hb < 8; ++hb) {
            accA[hb] = MFMA16(paA, vf[hb], accA[hb]);
            accB[hb] = MFMA16(paB, vf[hb], accB[hb]);
        }
        __builtin_amdgcn_s_setprio(0);
        __builtin_amdgcn_wave_barrier();
    }

    for (int off = 1; off < 16; off <<= 1)
        for (int i = 0; i < 4; ++i) {
            lsA[i] += __shfl_xor(lsA[i], off, 64);
            lsB[i] += __shfl_xor(lsB[i], off, 64);
        }
    if (c == 0)
        for (int i = 0; i < 4; ++i) {
            Pml[(size_t)sid * 32 + g * 4 + i]      = lsA[i];
            Pml[(size_t)sid * 32 + 16 + g * 4 + i] = lsB[i];
        }

    // Pacc transposed: po[col=128][row=32]; packed 8B stores
    bf16_t* po = Pacc + (size_t)sid * (32 * 128);
    for (int hb = 0; hb < 8; ++hb) {
        union { bf16_t h4[4]; unsigned long long u; } pa, pb;
        for (int i = 0; i < 4; ++i) {
            pa.h4[i] = (bf16_t)accA[hb][i];
            pb.h4[i] = (bf16_t)accB[hb][i];
        }
        bf16_t* cp = po + (hb * 16 + c) * 32;
        *reinterpret_cast<unsigned long long*>(cp + g * 4)      = pa.u;
        *reinterpret_cast<unsigned long long*>(cp + 16 + g * 4) = pb.u;
    }
}

// ---------------- combine partials (plain sums; Pacc is [col][row]) ----------------
// grid (64, 8, 4): each block sums 8 rows x 128 cols over count partials
__global__ __launch_bounds__(128) void combine_kernel(
    const bf16_t* __restrict__ Pacc, const float* __restrict__ Pml,
    float* __restrict__ out)
{
    __shared__ float invL[8];
    const int qt = blockIdx.x;                   // 0..63
    const int b  = blockIdx.y;
    const int qz = blockIdx.z;                   // row-quarter 0..3
    const int k  = qt >> 3;
    const int base  = b * UPB + 4 * k * (k + 1) + (qt & 7) * (k + 1);
    const int count = k + 1;
    const int tid = threadIdx.x;                 // = col 0..127

    if (tid < 8) {
        float L = 0.0f;
        for (int cu = 0; cu < count; ++cu)
            L += Pml[(size_t)(base + cu) * 32 + qz * 8 + tid];
        invL[tid] = 1.0f / L;
    }
    __syncthreads();

    float s[8];
    for (int r = 0; r < 8; ++r) s[r] = 0.0f;
    for (int cu = 0; cu < count; ++cu) {
        bf16x8 v = *(const bf16x8*)(
            Pacc + (size_t)(base + cu) * 4096 + tid * 32 + qz * 8);
        for (int j = 0; j < 8; ++j) s[j] += (float)v[j];
    }
    const int q0 = qt * 32 + qz * 8;
    for (int r = 0; r < 8; ++r)
        out[((size_t)b * TT + q0 + r) * HH + tid] = s[r] * invL[r];
}

extern "C" void kernel_launch(void* const* d_in, const int* in_sizes, int n_in,
                              void* d_out, int out_size, void* d_ws, size_t ws_size,
                              hipStream_t stream)
{
    const float* x  = (const float*)d_in[0];
    const float* Wq = (const float*)d_in[1];
    const float* Wk = (const float*)d_in[2];
    const float* Wv = (const float*)d_in[3];

    char* ws = (char*)d_ws;
    bf16_t* Wf   = (bf16_t*)ws;                       // 768 KB fragment-major
    bf16_t* Qf   = (bf16_t*)(ws + (1u  << 20));       // 4 MB fragment-major
    bf16_t* Kf   = (bf16_t*)(ws + (5u  << 20));       // 4 MB fragment-major
    bf16_t* Vf   = (bf16_t*)(ws + (9u  << 20));       // 4 MB fragment-major
    bf16_t* Pacc = (bf16_t*)(ws + (13u << 20));       // 2304*8192 B = 18.9 MB
    float*  Pml  = (float*) (ws + (32u << 20));       // 2304*128 B

    prep_w_kernel<<<1536, 256, 0, stream>>>(Wq, Wk, Wv, Wf);
    qkv_kernel<<<512, 256, 0, stream>>>(x, Wf, Qf, Kf, Vf);
    attn_kernel<<<576, 256, 0, stream>>>(Qf, Kf, Vf, Pacc, Pml);
    combine_kernel<<<dim3(64, 8, 4), 128, 0, stream>>>(Pacc, Pml, (float*)d_out);
}

// Round 17
// 66.102 us; speedup vs baseline: 1.2001x; 1.0079x over previous
//
#include <hip/hip_runtime.h>
#include <hip/hip_bf16.h>

typedef __bf16 bf16_t;
typedef bf16_t bf16x8 __attribute__((ext_vector_type(8)));
typedef bf16_t bf16x4 __attribute__((ext_vector_type(4)));
typedef float f32x4 __attribute__((ext_vector_type(4)));

#define MFMA16(a, b, c) __builtin_amdgcn_mfma_f32_16x16x32_bf16((a), (b), (c), 0, 0, 0)

// B=8, T=2048, E=1024, H=128
#define TT 2048
#define EE 1024
#define HH 128
#define UPB 576   // partial slots per batch: sum over 128 16-row qtiles of (qt>>4)+1

// Fragment-major layouts (every consumer load = one coalesced 64x16B instr):
//  Wf: chunk(ct,kt): lane(g,c) elem e = W_{ct>>3}[k=kt*32+g*8+e][n=(ct&7)*16+c]
//  Qf/Kf: chunk(grt,kk): lane(g,c) elem e = M[grt*16+c][kk*32+g*8+e]
//  Vf: chunk(b,vc,hb): lane(g,c) elem j = V[b][vc*32+g*8+j][hb*16+c]

// ---------------- prep: Wf fragment-major, f32 -> bf16 ----------------
__global__ __launch_bounds__(256) void prep_w_kernel(
    const float* __restrict__ Wq, const float* __restrict__ Wk,
    const float* __restrict__ Wv, bf16_t* __restrict__ Wf)
{
    int idx = blockIdx.x * 256 + threadIdx.x;   // 0 .. 393215
    int e  = idx & 7;
    int c  = (idx >> 3) & 15;
    int g  = (idx >> 7) & 3;
    int kt = (idx >> 9) & 31;
    int ct = idx >> 14;                          // 0..23
    int w  = ct >> 3;
    const float* W = (w == 0) ? Wq : (w == 1) ? Wk : Wv;
    int k = kt * 32 + g * 8 + e;
    int n = (ct & 7) * 16 + c;
    Wf[idx] = (bf16_t)W[k * HH + n];
}

// ---------------- fused QKV GEMM (R16 structure, unchanged) ----------------
__global__ __launch_bounds__(256) void qkv_kernel(
    const float* __restrict__ x, const bf16_t* __restrict__ Wf,
    bf16_t* __restrict__ Qf, bf16_t* __restrict__ Kf, bf16_t* __restrict__ Vf)
{
    __shared__ __attribute__((aligned(16))) bf16_t As[2][64][72];  // 144B rows
    const int bx = blockIdx.x;
    const int row0  = (bx & 255) * 64;
    const int nhalf = bx >> 8;
    const int tid  = threadIdx.x;
    const int lane = tid & 63;
    const int wn   = tid >> 6;                    // 4 waves: 48-col slices
    const int g = lane >> 4, c = lane & 15;

    const int srow = tid >> 2;
    const int scg  = tid & 3;
    const float* xp = x + (size_t)(row0 + srow) * EE + scg * 16;

    const bf16_t* wfb = Wf + ((size_t)(nhalf * 12 + wn * 3) * 32) * 512 + lane * 8;

    f32x4 acc[4][3];
    for (int i = 0; i < 4; ++i)
        for (int j = 0; j < 3; ++j) acc[i][j] = (f32x4)0.0f;

    f32x4 xa[3][4];                               // depth-3 x pipeline
    bf16x8 w[2][6];                               // [set][kk*3+j]

#define BAR() do {                                                            \
    asm volatile("s_waitcnt lgkmcnt(0)" ::: "memory");                        \
    __builtin_amdgcn_s_barrier();                                             \
    __builtin_amdgcn_sched_barrier(0);                                        \
} while (0)
#define XLOAD(S, T)                                                           \
    for (int q = 0; q < 4; ++q)                                               \
        xa[S][q] = *(const f32x4*)(xp + (size_t)(T) * 64 + q * 4);
#define WLOAD(S, T)                                                           \
    for (int kk = 0; kk < 2; ++kk)                                            \
        for (int j = 0; j < 3; ++j)                                           \
            w[S][kk * 3 + j] = *(const bf16x8*)(wfb +                         \
                ((size_t)j * 32 + (T) * 2 + kk) * 512);
#define XWRITE(S, BUF) do {                                                   \
    union { bf16_t h[8]; unsigned long long u[2]; } pA_, pB_;                 \
    for (int q = 0; q < 4; ++q) {                                             \
        pA_.h[q]     = (bf16_t)xa[S][0][q];                                   \
        pA_.h[4 + q] = (bf16_t)xa[S][1][q];                                   \
        pB_.h[q]     = (bf16_t)xa[S][2][q];                                   \
        pB_.h[4 + q] = (bf16_t)xa[S][3][q];                                   \
    }                                                                         \
    *reinterpret_cast<unsigned long long*>(&As[BUF][srow][scg * 16])     = pA_.u[0]; \
    *reinterpret_cast<unsigned long long*>(&As[BUF][srow][scg * 16 + 4]) = pA_.u[1]; \
    *reinterpret_cast<unsigned long long*>(&As[BUF][srow][scg * 16 + 8]) = pB_.u[0]; \
    *reinterpret_cast<unsigned long long*>(&As[BUF][srow][scg * 16 +12]) = pB_.u[1]; \
} while (0)

    XLOAD(0, 0);
    XLOAD(1, 1);
    XLOAD(2, 2);
    WLOAD(0, 0);
    WLOAD(1, 1);
    XWRITE(0, 0);
    BAR();

#pragma unroll
    for (int t = 0; t < 16; ++t) {
        const int buf = t & 1;
        if (t + 3 < 16) XLOAD((t + 3) % 3, t + 3);
        __builtin_amdgcn_s_setprio(1);
        for (int kk = 0; kk < 2; ++kk)
            for (int mt = 0; mt < 4; ++mt) {
                bf16x8 af = *(const bf16x8*)&As[buf][mt * 16 + c][kk * 32 + g * 8];
                for (int j = 0; j < 3; ++j)
                    acc[mt][j] = MFMA16(af, w[t & 1][kk * 3 + j], acc[mt][j]);
            }
        __builtin_amdgcn_s_setprio(0);
        if (t + 2 < 16) WLOAD(t & 1, t + 2);
        if (t + 1 < 16) XWRITE((t + 1) % 3, buf ^ 1);
        BAR();
    }
#undef XLOAD
#undef WLOAD
#undef XWRITE
#undef BAR

    const float sc = 0.08838834764831845f * 1.4426950408889634f; // 1/sqrt(128)*log2e
    for (int mt = 0; mt < 4; ++mt)
        for (int j = 0; j < 3; ++j) {
            int cb = nhalf * 192 + wn * 48 + j * 16;
            int w_ = cb >> 7;
            int hl = (cb & 127) + c;
            int t0 = row0 + mt * 16 + g * 4;
            if (w_ == 2) {
                int b  = t0 >> 11;
                int ttr = t0 & (TT - 1);
                int vc = ttr >> 5, gg = (ttr & 31) >> 3, j0 = ttr & 7;
                int hb = hl >> 4, cc = hl & 15;
                union { bf16_t h4[4]; unsigned long long u; } pk;
                for (int i = 0; i < 4; ++i) pk.h4[i] = (bf16_t)acc[mt][j][i];
                *reinterpret_cast<unsigned long long*>(
                    Vf + ((size_t)((b * 64 + vc) * 8 + hb)) * 512 +
                    (gg * 16 + cc) * 8 + j0) = pk.u;
            } else {
                bf16_t* dst = (w_ == 0) ? Qf : Kf;
                float s = (w_ == 0) ? sc : 1.0f;
                int kk = hl >> 5, gg = (hl & 31) >> 3, e = hl & 7;
                int grt = t0 >> 4;
                for (int i = 0; i < 4; ++i) {
                    int cr = (t0 + i) & 15;
                    dst[((size_t)(grt * 4 + kk)) * 512 + (gg * 16 + cr) * 8 + e] =
                        (bf16_t)(acc[mt][j][i] * s);
                }
            }
        }
}

// ---------------- flash attention: 16-row units for 2x TLP ----------------
// unit = (b, 16-row qtile, kvchunk256); one wave per unit, 4 units/block.
// 4608 waves = 4.5/SIMD launched. blockIdx&7 = b (XCD-pinned batch).
// All Q/K/V loads coalesced fragment-major; no-max softmax (exp2, log2e in Q).
__global__ __launch_bounds__(256) void attn_kernel(
    const bf16_t* __restrict__ Qf, const bf16_t* __restrict__ Kf,
    const bf16_t* __restrict__ Vf, bf16_t* __restrict__ Pacc,
    float* __restrict__ Pml)
{
    __shared__ __attribute__((aligned(16))) bf16_t Pl[4][16][40];
    const int tid = threadIdx.x, lane = tid & 63, wid = tid >> 6;
    const int g = lane >> 4, c = lane & 15;
    bf16_t (*P)[40] = Pl[wid];

    const int bx = blockIdx.x;
    const int b  = bx & 7;                       // XCD-pinned batch
    const int u  = 575 - ((bx >> 3) * 4 + wid);  // long-units-first
    int k = 0;
    while (8 * (k + 1) * (k + 2) <= u) ++k;      // tier k = qt>>4, 0..7
    const int r  = u - 8 * k * (k + 1);
    const int qt = 16 * k + r / (k + 1);
    const int ch = r - (r / (k + 1)) * (k + 1);
    const int q0 = qt * 16;
    const int kv_lo = ch * 256;
    int kv_hi = kv_lo + 256; if (kv_hi > q0 + 16) kv_hi = q0 + 16;
    const int sid = b * UPB + 8 * k * (k + 1) + (qt & 15) * (k + 1) + ch;

    bf16x8 qf[4];
    for (int kk = 0; kk < 4; ++kk)
        qf[kk] = *(const bf16x8*)(Qf +
            ((size_t)((b * 128 + qt) * 4 + kk)) * 512 + lane * 8);

    f32x4 acc[8];
    for (int hb = 0; hb < 8; ++hb) acc[hb] = (f32x4)0.0f;
    float ls[4] = {0, 0, 0, 0};

    for (int kv0 = kv_lo; kv0 < kv_hi; kv0 += 32) {
        const int kt = b * 128 + (kv0 >> 4);
        bf16x8 k0f[4], k1f[4], vf[8];
        for (int kk = 0; kk < 4; ++kk) {
            k0f[kk] = *(const bf16x8*)(Kf + ((size_t)(kt * 4 + kk)) * 512 + lane * 8);
            k1f[kk] = *(const bf16x8*)(Kf + ((size_t)((kt + 1) * 4 + kk)) * 512 + lane * 8);
        }
        const int vcb = (b * 64 + (kv0 >> 5)) * 8;
        for (int hb = 0; hb < 8; ++hb)
            vf[hb] = *(const bf16x8*)(Vf + ((size_t)(vcb + hb)) * 512 + lane * 8);

        f32x4 s0 = (f32x4)0.0f, s1 = (f32x4)0.0f;
        for (int kk = 0; kk < 4; ++kk) {
            s0 = MFMA16(qf[kk], k0f[kk], s0);
            s1 = MFMA16(qf[kk], k1f[kk], s1);
        }
        if (kv0 + 32 > q0) {                     // diagonal tiles: causal mask
            for (int i = 0; i < 4; ++i) {
                int row = q0 + g * 4 + i;
                if (kv0 + c > row)      s0[i] = -1e30f;
                if (kv0 + 16 + c > row) s1[i] = -1e30f;
            }
        }
        float p0[4], p1[4];
        for (int i = 0; i < 4; ++i) {            // p = 2^s (log2e folded into Q)
            p0[i] = exp2f(s0[i]);
            p1[i] = exp2f(s1[i]);
            ls[i] += p0[i] + p1[i];
        }
        for (int i = 0; i < 4; ++i) {
            P[g * 4 + i][c]      = (bf16_t)p0[i];
            P[g * 4 + i][c + 16] = (bf16_t)p1[i];
        }
        __builtin_amdgcn_wave_barrier();
        asm volatile("s_waitcnt lgkmcnt(0)" ::: "memory");
        __builtin_amdgcn_sched_barrier(0);
        bf16x8 pa = *(const bf16x8*)&P[c][g * 8];
        __builtin_amdgcn_s_setprio(1);
        for (int hb = 0; hb < 8; ++hb)
            acc[hb] = MFMA16(pa, vf[hb], acc[hb]);
        __builtin_amdgcn_s_setprio(0);
        __builtin_amdgcn_wave_barrier();
    }

    for (int off = 1; off < 16; off <<= 1)
        for (int i = 0; i < 4; ++i) ls[i] += __shfl_xor(ls[i], off, 64);
    if (c == 0)
        for (int i = 0; i < 4; ++i)
            Pml[(size_t)sid * 16 + g * 4 + i] = ls[i];

    // Pacc transposed: po[col=128][row=16]; packed 8B stores
    bf16_t* po = Pacc + (size_t)sid * (16 * 128);
    for (int hb = 0; hb < 8; ++hb) {
        union { bf16_t h4[4]; unsigned long long u; } pk;
        for (int i = 0; i < 4; ++i) pk.h4[i] = (bf16_t)acc[hb][i];
        *reinterpret_cast<unsigned long long*>(
            po + (hb * 16 + c) * 16 + g * 4) = pk.u;
    }
}

// ---------------- combine partials (plain sums; Pacc is [col][row=16]) ----------------
// grid (128, 8, 2): each block sums 8 rows x 128 cols over count partials
__global__ __launch_bounds__(128) void combine_kernel(
    const bf16_t* __restrict__ Pacc, const float* __restrict__ Pml,
    float* __restrict__ out)
{
    __shared__ float invL[8];
    const int qt = blockIdx.x;                   // 0..127
    const int b  = blockIdx.y;
    const int qz = blockIdx.z;                   // row-half 0..1
    const int k  = qt >> 4;
    const int base  = b * UPB + 8 * k * (k + 1) + (qt & 15) * (k + 1);
    const int count = k + 1;
    const int tid = threadIdx.x;                 // = col 0..127

    if (tid < 8) {
        float L = 0.0f;
        for (int cu = 0; cu < count; ++cu)
            L += Pml[(size_t)(base + cu) * 16 + qz * 8 + tid];
        invL[tid] = 1.0f / L;
    }
    __syncthreads();

    float s[8];
    for (int r = 0; r < 8; ++r) s[r] = 0.0f;
    for (int cu = 0; cu < count; ++cu) {
        bf16x8 v = *(const bf16x8*)(
            Pacc + (size_t)(base + cu) * 2048 + tid * 16 + qz * 8);
        for (int j = 0; j < 8; ++j) s[j] += (float)v[j];
    }
    const int q0 = qt * 16 + qz * 8;
    for (int r = 0; r < 8; ++r)
        out[((size_t)b * TT + q0 + r) * HH + tid] = s[r] * invL[r];
}

extern "C" void kernel_launch(void* const* d_in, const int* in_sizes, int n_in,
                              void* d_out, int out_size, void* d_ws, size_t ws_size,
                              hipStream_t stream)
{
    const float* x  = (const float*)d_in[0];
    const float* Wq = (const float*)d_in[1];
    const float* Wk = (const float*)d_in[2];
    const float* Wv = (const float*)d_in[3];

    char* ws = (char*)d_ws;
    bf16_t* Wf   = (bf16_t*)ws;                       // 768 KB fragment-major
    bf16_t* Qf   = (bf16_t*)(ws + (1u  << 20));       // 4 MB fragment-major
    bf16_t* Kf   = (bf16_t*)(ws + (5u  << 20));       // 4 MB fragment-major
    bf16_t* Vf   = (bf16_t*)(ws + (9u  << 20));       // 4 MB fragment-major
    bf16_t* Pacc = (bf16_t*)(ws + (13u << 20));       // 4608*4096 B = 18.9 MB
    float*  Pml  = (float*) (ws + (32u << 20));       // 4608*64 B

    prep_w_kernel<<<1536, 256, 0, stream>>>(Wq, Wk, Wv, Wf);
    qkv_kernel<<<512, 256, 0, stream>>>(x, Wf, Qf, Kf, Vf);
    attn_kernel<<<1152, 256, 0, stream>>>(Qf, Kf, Vf, Pacc, Pml);
    combine_kernel<<<dim3(128, 8, 2), 128, 0, stream>>>(Pacc, Pml, (float*)d_out);
}